// Round 9
// baseline (389.711 us; speedup 1.0000x reference)
//
#include <hip/hip_runtime.h>

#define NPTS   131072
#define CIN    1018
#define DIN    1024
#define COUT   128
#define BB     16
#define GDIM   32
#define NCELLS (BB*GDIM*GDIM*GDIM)   // 524288
#define NREP   8                     // gstats replication (atomic contention)

typedef float          f32x4  __attribute__((ext_vector_type(4)));
typedef __bf16         bf16x8 __attribute__((ext_vector_type(8)));
typedef unsigned short us8    __attribute__((ext_vector_type(8)));

__device__ __forceinline__ unsigned short f2bf(float f) {
    union { float f; unsigned u; } v; v.f = f;
    unsigned r = v.u + 0x7FFFu + ((v.u >> 16) & 1u);   // RNE
    return (unsigned short)(r >> 16);
}

__device__ __forceinline__ f32x4 MF(us8 a, us8 b, f32x4 c) {
    return __builtin_amdgcn_mfma_f32_16x16x32_bf16(
        __builtin_bit_cast(bf16x8, a), __builtin_bit_cast(bf16x8, b), c, 0, 0, 0);
}

// ---- zero scratch ----------------------------------------------------------
__global__ __launch_bounds__(256) void k_zero(int4* __restrict__ p, int n4) {
    const int idx = blockIdx.x * 256 + threadIdx.x;
    const int4 z = {0, 0, 0, 0};
    for (int i = idx; i < n4; i += 131072) p[i] = z;
}

// ---- pack W1 (1024x128 f32) into MFMA-B-fragment-ordered bf16 --------------
// pw[((ks*8+cb)*64 + l)*8 + i] = bf16( W1[ks*32 + (l>>4)*8 + i][cb*16 + (l&15)] )
__global__ __launch_bounds__(256) void k_packW(const float* __restrict__ W1,
                                               unsigned short* __restrict__ pw) {
    const int t  = blockIdx.x * 256 + threadIdx.x;   // 0..16383
    const int l  = t & 63;
    const int cb = (t >> 6) & 7;
    const int ks = t >> 9;
    const int col  = cb * 16 + (l & 15);
    const int krow = ks * 32 + ((l >> 4) * 8);
    unsigned short* dst = pw + (size_t)t * 8;
#pragma unroll
    for (int i = 0; i < 8; ++i) dst[i] = f2bf(W1[(size_t)(krow + i) * COUT + col]);
}

// ---- prep: cell ids, tail {off0,off1,off2,x,y,z,0,0}, int counts -----------
__global__ __launch_bounds__(256) void k_prep(const float* __restrict__ xyz,
                                              const float* __restrict__ nocs,
                                              const int*   __restrict__ bidx,
                                              float* __restrict__ tail,
                                              int*   __restrict__ cellid,
                                              int*   __restrict__ cnt) {
    const int i = blockIdx.x * 256 + threadIdx.x;
    if (i >= NPTS) return;
    int id[3]; float off[3];
#pragma unroll
    for (int d = 0; d < 3; ++d) {
        const float nv = nocs[i * 3 + d];
        int ii = (int)rintf(nv * 31.0f);              // jnp.round = half-to-even = rintf
        ii = ii < 0 ? 0 : (ii > 31 ? 31 : ii);
        id[d]  = ii;
        off[d] = nv - (float)ii / 31.0f;
    }
    float* tl = tail + (size_t)i * 8;
    tl[0] = off[0]; tl[1] = off[1]; tl[2] = off[2];
    tl[3] = xyz[i*3+0]; tl[4] = xyz[i*3+1]; tl[5] = xyz[i*3+2];
    tl[6] = 0.f; tl[7] = 0.f;
    const int cell = ((bidx[i] * GDIM + id[0]) * GDIM + id[1]) * GDIM + id[2];
    cellid[i] = cell;
    atomicAdd(&cnt[cell], 1);
}

// ---- exclusive scan of 524288 counts ---------------------------------------
__global__ __launch_bounds__(256) void k_scanA(const int* __restrict__ cnt,
                                               int* __restrict__ rel,
                                               int* __restrict__ bsum) {
    __shared__ int wtot[4], woff[4];
    const int t = threadIdx.x, blk = blockIdx.x;
    const int4 c4 = *(const int4*)&cnt[blk * 1024 + t * 4];
    const int s = c4.x + c4.y + c4.z + c4.w;
    int v = s;
    const int lane = t & 63, w = t >> 6;
#pragma unroll
    for (int d = 1; d < 64; d <<= 1) {
        const int u = __shfl_up(v, d);
        if (lane >= d) v += u;
    }
    if (lane == 63) wtot[w] = v;
    __syncthreads();
    if (t == 0) {
        int a = 0;
#pragma unroll
        for (int i = 0; i < 4; ++i) { woff[i] = a; a += wtot[i]; }
        bsum[blk] = a;
    }
    __syncthreads();
    const int excl = woff[w] + v - s;
    int* r = rel + blk * 1024 + t * 4;
    r[0] = excl; r[1] = excl + c4.x;
    r[2] = excl + c4.x + c4.y; r[3] = excl + c4.x + c4.y + c4.z;
}

__global__ __launch_bounds__(256) void k_scanB(const int* __restrict__ bsum,
                                               int* __restrict__ boff) {
    __shared__ int wtot[4], woff[4];
    const int t = threadIdx.x;
    const int2 c2 = *(const int2*)&bsum[t * 2];
    const int s = c2.x + c2.y;
    int v = s;
    const int lane = t & 63, w = t >> 6;
#pragma unroll
    for (int d = 1; d < 64; d <<= 1) {
        const int u = __shfl_up(v, d);
        if (lane >= d) v += u;
    }
    if (lane == 63) wtot[w] = v;
    __syncthreads();
    if (t == 0) {
        int a = 0;
#pragma unroll
        for (int i = 0; i < 4; ++i) { woff[i] = a; a += wtot[i]; }
    }
    __syncthreads();
    const int excl = woff[w] + v - s;
    boff[t * 2] = excl; boff[t * 2 + 1] = excl + c2.x;
}

// ---- fill: sorted destination row per point --------------------------------
__global__ __launch_bounds__(256) void k_fill(const int* __restrict__ cellid,
                                              const int* __restrict__ rel,
                                              const int* __restrict__ boff,
                                              int* __restrict__ cursor,
                                              int* __restrict__ dstrow) {
    const int i = blockIdx.x * 256 + threadIdx.x;
    if (i >= NPTS) return;
    const int cell = cellid[i];
    const int slot = atomicAdd(&cursor[cell], 1);
    dstrow[i] = rel[cell] + boff[cell >> 10] + slot;
}

// ---- fused GEMM v2: SEQUENTIAL-stream staging ------------------------------
// Tile = 16 rows = ONE contiguous 65KB span of feats. Stage: grid-stride
// float2 over the span (wave = 512B contiguous, walking forward -- the same
// pattern the 6.9TB/s fill uses; 509 float2/row divides exactly, no straddle).
// Convert f32->bf16 in-reg, ds_write into XOR-swizzled [16][1024] bf16 tile.
// Compute: 16 K-chunks, B frags reg-ping-pong from L2-resident pw, no barriers
// in the K loop. Theory: kills the ~32K-concurrent-row-stream DRAM-page thrash
// that capped every row-parallel variant (R2..R8) at ~2.3 TB/s.

template<int DIRECT>
__global__ __launch_bounds__(256) void k_gemm2(const float* __restrict__ feats,
                                               const float* __restrict__ tail,
                                               const int*   __restrict__ dstrow, // sorted row (A) or cellid (B)
                                               const float* __restrict__ b1,
                                               const unsigned short* __restrict__ pw,
                                               float* __restrict__ dst,          // h (A) or out (B)
                                               float* __restrict__ gstats) {
    __shared__ unsigned As[16 * 512];   // [row][128 granules of 16B][4 words], slot = g^(row&7)
    const int t = threadIdx.x;
    const int w = t >> 6, l = t & 63;
    const int kgrp = l >> 4, l15 = l & 15;
    const int row0 = blockIdx.x * 16;

    // ---- stage: sequential span read (8144 float2 = 16 rows x 1018 f32) ----
    const float2* span = (const float2*)(feats + (size_t)row0 * CIN);   // 8B-aligned
    for (int f = t; f < 8144; f += 256) {
        const float2 v = span[f];
        const unsigned r16 = (unsigned)f / 509u;          // const-div -> mul_hi
        const int k2 = f - (int)r16 * 509;                // k = 2*k2
        const unsigned pk = (unsigned)f2bf(v.x) | ((unsigned)f2bf(v.y) << 16);
        const int slot = (k2 >> 2) ^ (int)(r16 & 7u);
        As[(int)r16 * 512 + slot * 4 + (k2 & 3)] = pk;
    }
    if (t < 96) {                                         // k = 1018..1023 from tail
        const int r = t / 6, d = t - r * 6;
        const int k = 1018 + d;
        const int slot = 127 ^ (r & 7);
        ((unsigned short*)As)[r * 1024 + slot * 8 + (k & 7)] = f2bf(tail[(size_t)(row0 + r) * 8 + d]);
    }
    __syncthreads();

    // ---- compute: wave w owns cols w*32 .. w*32+31 (cbb 0,1) ----
    f32x4 acc[2];
#pragma unroll
    for (int cbb = 0; cbb < 2; ++cbb) { acc[cbb][0]=0.f; acc[cbb][1]=0.f; acc[cbb][2]=0.f; acc[cbb][3]=0.f; }
    us8 BX[2][2], BY[2][2];

#define LOADB2(B, ch) do{                                                 \
    _Pragma("unroll")                                                     \
    for (int _ks = 0; _ks < 2; ++_ks)                                     \
        _Pragma("unroll")                                                 \
        for (int _cbb = 0; _cbb < 2; ++_cbb)                              \
            B[_ks][_cbb] = *(const us8*)(pw +                             \
                ((((ch)*2 + _ks)*8 + (w*2 + _cbb))*64 + l)*8);            \
}while(0)

    LOADB2(BX, 0);
#pragma unroll
    for (int ch = 0; ch < 16; ++ch) {
        if (ch + 1 < 16) { if (ch & 1) LOADB2(BX, ch + 1); else LOADB2(BY, ch + 1); }
        const us8 (*cur)[2] = (ch & 1) ? BY : BX;
#pragma unroll
        for (int ks = 0; ks < 2; ++ks) {
            const int g = ch * 8 + ks * 4 + kgrp;
            const int slot = g ^ (l15 & 7);
            const us8 a = *(const us8*)&As[l15 * 512 + slot * 4];
            acc[0] = MF(a, cur[ks][0], acc[0]);
            acc[1] = MF(a, cur[ks][1], acc[1]);
        }
    }
#undef LOADB2

    // ---- epilogue: bias+relu; A: dense store at sorted row; B: atomic ------
    int rr[4];
#pragma unroll
    for (int j = 0; j < 4; ++j)
        rr[j] = dstrow[row0 + kgrp * 4 + j];    // C/D: row=(l>>4)*4+reg, col=l&15
    float* grep = gstats + (size_t)((blockIdx.x * 4 + w) & (NREP - 1)) * 256;
#pragma unroll
    for (int cbb = 0; cbb < 2; ++cbb) {
        const int c = w * 32 + cbb * 16 + l15;
        const float bias = b1[c];
        float s = 0.f, q = 0.f;
#pragma unroll
        for (int j = 0; j < 4; ++j) {
            float v0 = acc[cbb][j] + bias; v0 = v0 > 0.f ? v0 : 0.f;
            if (DIRECT) {
                const int a = rr[j];                       // dstrow==cellid here
                unsafeAtomicAdd(dst + (((size_t)((a >> 15) * COUT + c)) << 15) + (a & 32767), v0);
            } else {
                dst[(size_t)rr[j] * COUT + c] = v0;        // sorted dense store
            }
            s += v0; q += v0 * v0;
        }
        s += __shfl_xor(s, 16); s += __shfl_xor(s, 32);
        q += __shfl_xor(q, 16); q += __shfl_xor(q, 32);
        if (l < 16) {
            unsafeAtomicAdd(grep + c, s);
            unsafeAtomicAdd(grep + COUT + c, q);
        }
    }
}

// ---- finalize BN affine ----------------------------------------------------
__global__ void k_stats(const float* __restrict__ gstats, const float* __restrict__ g1,
                        const float* __restrict__ be1, float* __restrict__ ss) {
    const int c = threadIdx.x;   // 128
    float sm = 0.f, sq = 0.f;
#pragma unroll
    for (int r = 0; r < NREP; ++r) {
        sm += gstats[r * 256 + c];
        sq += gstats[r * 256 + COUT + c];
    }
    const float invn = 1.0f / (float)NPTS;
    const float mean = sm * invn;
    float var = sq * invn - mean * mean;
    var = var < 0.f ? 0.f : var;
    const float sc = g1[c] * rsqrtf(var + 1e-5f);
    ss[c] = sc;
    ss[COUT + c] = be1[c] - mean * sc;
}

// ---- gather sorted h rows per cell (sequential), mean+BN, transpose, store -
__global__ __launch_bounds__(256) void k_out(const float* __restrict__ h,
                                             const int* __restrict__ cnt,
                                             const int* __restrict__ rel,
                                             const int* __restrict__ boff,
                                             const float* __restrict__ ss,
                                             float* __restrict__ out) {
    __shared__ float tile[128 * 128];   // addr(c,j) = c*128 + (j ^ (c&28))
    __shared__ float linv[128];
    __shared__ float lss[256];
    const int t  = threadIdx.x;
    const int s0 = blockIdx.x * 128;
    const int b = s0 >> 15, sp0 = s0 & 32767;
    const int boff0 = boff[s0 >> 10];
    if (t < 128) {
        const int cn = cnt[s0 + t];
        linv[t] = cn > 0 ? 1.0f / (float)cn : 0.f;
    } else {
        const int c = t - 128;
        lss[c] = ss[c]; lss[128 + c] = ss[COUT + c];
    }
    const int q = t & 31, r8 = t >> 5;
#pragma unroll
    for (int rep = 0; rep < 16; ++rep) {
        const int j = r8 + rep * 8;
        const int cj = cnt[s0 + j];
        if (cj > 0) {
            const int st = rel[s0 + j] + boff0;
            f32x4 v; v[0] = v[1] = v[2] = v[3] = 0.f;
            for (int k = 0; k < cj; ++k) {
                const f32x4 hv = *(const f32x4*)&h[(size_t)(st + k) * COUT + q * 4];
                v[0] += hv[0]; v[1] += hv[1]; v[2] += hv[2]; v[3] += hv[3];
            }
#pragma unroll
            for (int d = 0; d < 4; ++d) {
                const int c = q * 4 + d;
                tile[c * 128 + (j ^ (c & 28))] = v[d];
            }
        }
    }
    __syncthreads();
#pragma unroll
    for (int p = 0; p < 16; ++p) {
        const int c = p * 8 + r8;
        const float sc = lss[c], sh = lss[128 + c];
        const int u = c & 28;
        const f32x4 vv = *(const f32x4*)&tile[c * 128 + ((q * 4) ^ u)];
        f32x4 o;
#pragma unroll
        for (int d = 0; d < 4; ++d) {
            const float inv = linv[q * 4 + d];
            o[d] = inv > 0.f ? vv[d] * inv * sc + sh : 0.f;
        }
        *(f32x4*)&out[(((size_t)(b * COUT + c)) << 15) + sp0 + q * 4] = o;
    }
}

// ---- fallback normalize (plan B) -------------------------------------------
__global__ __launch_bounds__(256) void k_norm_inplace(float* __restrict__ out,
                                                      const int* __restrict__ cnt,
                                                      const float* __restrict__ ss,
                                                      size_t total) {
    const size_t i = ((size_t)blockIdx.x * 256 + threadIdx.x) * 4;
    if (i >= total) return;
    const int c = (int)((i >> 15) & 127);
    const size_t cellb = ((i >> 22) << 15) | (i & 32767);
    f32x4 v = *(f32x4*)&out[i];
    const int4 cn = *(const int4*)&cnt[cellb];
    const float sc = ss[c], sh = ss[COUT + c];
    const int cna[4] = {cn.x, cn.y, cn.z, cn.w};
#pragma unroll
    for (int d = 0; d < 4; ++d)
        v[d] = cna[d] > 0 ? v[d] / (float)cna[d] * sc + sh : 0.f;
    *(f32x4*)&out[i] = v;
}

extern "C" void kernel_launch(void* const* d_in, const int* in_sizes, int n_in,
                              void* d_out, int out_size, void* d_ws, size_t ws_size,
                              hipStream_t stream) {
    const float* xyz   = (const float*)d_in[0];
    const float* nocs  = (const float*)d_in[1];
    const float* feats = (const float*)d_in[2];
    const int*   bidx  = (const int*)d_in[4];
    const float* W1    = (const float*)d_in[6];
    const float* b1    = (const float*)d_in[7];
    const float* g1    = (const float*)d_in[8];
    const float* be1   = (const float*)d_in[9];
    float* out = (float*)d_out;
    float* ws  = (float*)d_ws;

    const size_t HF  = (size_t)NPTS * COUT;               // 16,777,216 floats
    const size_t STF = NREP * 256;
    // plan A (4B units): h | cnt | cur | st | rel | bof | dstrow | ss | tail | cid | pw
    const size_t oA_h    = 0;
    const size_t oA_cnt  = HF;
    const size_t oA_cur  = oA_cnt + NCELLS;
    const size_t oA_st   = oA_cur + NCELLS;
    const size_t oA_rel  = oA_st + STF;
    const size_t oA_bof  = oA_rel + NCELLS;
    const size_t oA_dr   = oA_bof + 512;
    const size_t oA_ss   = oA_dr + NPTS;
    const size_t oA_tail = oA_ss + 256;
    const size_t oA_cid  = oA_tail + (size_t)NPTS * 8;
    const size_t oA_pw   = oA_cid + NPTS;
    const size_t needA   = (oA_pw + 65536) * sizeof(float);   // pw = 131072 u16
    const bool planA = ws_size >= needA;

    // plan B (4B units): cnt | st | ss | tail | cid | pw
    const size_t oB_cnt = 0, oB_st = NCELLS, oB_ss = oB_st + STF,
                 oB_tail = oB_ss + 256, oB_cid = oB_tail + (size_t)NPTS * 8,
                 oB_pw = oB_cid + NPTS;

    float* h   = planA ? ws + oA_h : nullptr;
    int*   cnt = (int*)(ws + (planA ? oA_cnt : oB_cnt));
    int*   cur = planA ? (int*)(ws + oA_cur) : nullptr;
    float* st  = ws + (planA ? oA_st : oB_st);
    int*   rel = planA ? (int*)(ws + oA_rel) : nullptr;
    int*   bof = planA ? (int*)(ws + oA_bof) : nullptr;
    int*   dr  = planA ? (int*)(ws + oA_dr) : nullptr;
    float* ssb = ws + (planA ? oA_ss : oB_ss);
    float* tl  = ws + (planA ? oA_tail : oB_tail);
    int*   cid = (int*)(ws + (planA ? oA_cid : oB_cid));
    unsigned short* pw = (unsigned short*)(ws + (planA ? oA_pw : oB_pw));

    if (planA) {
        k_zero<<<512, 256, 0, stream>>>((int4*)cnt, (int)((2 * NCELLS + STF) / 4));
    } else {
        k_zero<<<512, 256, 0, stream>>>((int4*)cnt, (int)((NCELLS + STF) / 4));
        hipMemsetAsync(out, 0, (size_t)out_size * sizeof(float), stream);
    }

    k_packW<<<64, 256, 0, stream>>>(W1, pw);
    k_prep<<<NPTS / 256, 256, 0, stream>>>(xyz, nocs, bidx, tl, cid, cnt);
    if (planA) {
        k_scanA<<<512, 256, 0, stream>>>(cnt, rel, bof);
        k_scanB<<<1, 256, 0, stream>>>(bof, bof);
        k_fill<<<NPTS / 256, 256, 0, stream>>>(cid, rel, bof, cur, dr);
        k_gemm2<0><<<NPTS / 16, 256, 0, stream>>>(feats, tl, dr, b1, pw, h, st);
        k_stats<<<1, 128, 0, stream>>>(st, g1, be1, ssb);
        k_out<<<NCELLS / 128, 256, 0, stream>>>(h, cnt, rel, bof, ssb, out);
    } else {
        k_gemm2<1><<<NPTS / 16, 256, 0, stream>>>(feats, tl, cid, b1, pw, out, st);
        k_stats<<<1, 128, 0, stream>>>(st, g1, be1, ssb);
        const size_t total = (size_t)out_size;
        k_norm_inplace<<<(unsigned)((total + 1023) / 1024), 256, 0, stream>>>(out, cnt, ssb, total);
    }
    (void)in_sizes; (void)n_in; (void)d_in;
}

// Round 10
// 306.810 us; speedup vs baseline: 1.2702x; 1.2702x over previous
//
#include <hip/hip_runtime.h>

#define NPTS   131072
#define CIN    1018
#define DIN    1024
#define COUT   128
#define BB     16
#define GDIM   32
#define NCELLS (BB*GDIM*GDIM*GDIM)   // 524288
#define NREP   8                     // gstats replication (atomic contention)

typedef float          f32x4  __attribute__((ext_vector_type(4)));
typedef __bf16         bf16x8 __attribute__((ext_vector_type(8)));
typedef unsigned short us8    __attribute__((ext_vector_type(8)));

__device__ __forceinline__ unsigned short f2bf(float f) {
    union { float f; unsigned u; } v; v.f = f;
    unsigned r = v.u + 0x7FFFu + ((v.u >> 16) & 1u);   // RNE
    return (unsigned short)(r >> 16);
}

__device__ __forceinline__ us8 cvt8f(f32x4 lo, f32x4 hi) {
    bf16x8 r;
    r[0] = (__bf16)lo[0]; r[1] = (__bf16)lo[1]; r[2] = (__bf16)lo[2]; r[3] = (__bf16)lo[3];
    r[4] = (__bf16)hi[0]; r[5] = (__bf16)hi[1]; r[6] = (__bf16)hi[2]; r[7] = (__bf16)hi[3];
    return __builtin_bit_cast(us8, r);
}

__device__ __forceinline__ f32x4 MF(us8 a, us8 b, f32x4 c) {
    return __builtin_amdgcn_mfma_f32_16x16x32_bf16(
        __builtin_bit_cast(bf16x8, a), __builtin_bit_cast(bf16x8, b), c, 0, 0, 0);
}

// ---- merged: pack W1 (blocks 0..63) + zero scratch (blocks 64..) -----------
// pw[((ks*8+cb)*64 + l)*8 + i] = bf16( W1[ks*32 + (l>>4)*8 + i][cb*16 + (l&15)] )
__global__ __launch_bounds__(256) void k_zp(const float* __restrict__ W1,
                                            unsigned short* __restrict__ pw,
                                            int4* __restrict__ zp, int n4) {
    const int t = threadIdx.x;
    if (blockIdx.x < 64) {
        const int g  = blockIdx.x * 256 + t;   // 0..16383
        const int l  = g & 63;
        const int cb = (g >> 6) & 7;
        const int ks = g >> 9;
        const int col  = cb * 16 + (l & 15);
        const int krow = ks * 32 + ((l >> 4) * 8);
        unsigned short* dst = pw + (size_t)g * 8;
#pragma unroll
        for (int i = 0; i < 8; ++i) dst[i] = f2bf(W1[(size_t)(krow + i) * COUT + col]);
    } else {
        const int idx = (blockIdx.x - 64) * 256 + t;
        const int4 z = {0, 0, 0, 0};
        for (int i = idx; i < n4; i += 512 * 256) zp[i] = z;
    }
}

// ---- prep: cell ids, tail group {f1016,f1017,off*3,xyz*3}, int counts ------
__global__ __launch_bounds__(256) void k_prep(const float* __restrict__ xyz,
                                              const float* __restrict__ nocs,
                                              const float* __restrict__ feats,
                                              const int*   __restrict__ bidx,
                                              float* __restrict__ tail,
                                              int*   __restrict__ cellid,
                                              int*   __restrict__ cnt) {
    const int i = blockIdx.x * 256 + threadIdx.x;
    if (i >= NPTS) return;
    int id[3]; float off[3];
#pragma unroll
    for (int d = 0; d < 3; ++d) {
        const float nv = nocs[i * 3 + d];
        int ii = (int)rintf(nv * 31.0f);              // jnp.round = half-to-even = rintf
        ii = ii < 0 ? 0 : (ii > 31 ? 31 : ii);
        id[d]  = ii;
        off[d] = nv - (float)ii / 31.0f;
    }
    float* tl = tail + (size_t)i * 8;
    tl[0] = feats[(size_t)i * CIN + 1016];
    tl[1] = feats[(size_t)i * CIN + 1017];
    tl[2] = off[0]; tl[3] = off[1]; tl[4] = off[2];
    tl[5] = xyz[i*3+0]; tl[6] = xyz[i*3+1]; tl[7] = xyz[i*3+2];
    const int cell = ((bidx[i] * GDIM + id[0]) * GDIM + id[1]) * GDIM + id[2];
    cellid[i] = cell;
    atomicAdd(&cnt[cell], 1);
}

// ---- exclusive scan of 524288 counts (also zeroes cursor for k_fill) -------
__global__ __launch_bounds__(256) void k_scanA(const int* __restrict__ cnt,
                                               int* __restrict__ rel,
                                               int* __restrict__ bsum,
                                               int4* __restrict__ cursor) {
    __shared__ int wtot[4], woff[4];
    const int t = threadIdx.x, blk = blockIdx.x;
    const int4 z = {0, 0, 0, 0};
    cursor[blk * 256 + t] = z;                  // zero cursor (saves k_zero span)
    const int4 c4 = *(const int4*)&cnt[blk * 1024 + t * 4];
    const int s = c4.x + c4.y + c4.z + c4.w;
    int v = s;
    const int lane = t & 63, w = t >> 6;
#pragma unroll
    for (int d = 1; d < 64; d <<= 1) {
        const int u = __shfl_up(v, d);
        if (lane >= d) v += u;
    }
    if (lane == 63) wtot[w] = v;
    __syncthreads();
    if (t == 0) {
        int a = 0;
#pragma unroll
        for (int i = 0; i < 4; ++i) { woff[i] = a; a += wtot[i]; }
        bsum[blk] = a;
    }
    __syncthreads();
    const int excl = woff[w] + v - s;
    int* r = rel + blk * 1024 + t * 4;
    r[0] = excl; r[1] = excl + c4.x;
    r[2] = excl + c4.x + c4.y; r[3] = excl + c4.x + c4.y + c4.z;
}

__global__ __launch_bounds__(256) void k_scanB(const int* __restrict__ bsum,
                                               int* __restrict__ boff) {
    __shared__ int wtot[4], woff[4];
    const int t = threadIdx.x;
    const int2 c2 = *(const int2*)&bsum[t * 2];
    const int s = c2.x + c2.y;
    int v = s;
    const int lane = t & 63, w = t >> 6;
#pragma unroll
    for (int d = 1; d < 64; d <<= 1) {
        const int u = __shfl_up(v, d);
        if (lane >= d) v += u;
    }
    if (lane == 63) wtot[w] = v;
    __syncthreads();
    if (t == 0) {
        int a = 0;
#pragma unroll
        for (int i = 0; i < 4; ++i) { woff[i] = a; a += wtot[i]; }
    }
    __syncthreads();
    const int excl = woff[w] + v - s;
    boff[t * 2] = excl; boff[t * 2 + 1] = excl + c2.x;
}

// ---- fill: sorted destination row per point --------------------------------
__global__ __launch_bounds__(256) void k_fill(const int* __restrict__ cellid,
                                              const int* __restrict__ rel,
                                              const int* __restrict__ boff,
                                              int* __restrict__ cursor,
                                              int* __restrict__ dstrow) {
    const int i = blockIdx.x * 256 + threadIdx.x;
    if (i >= NPTS) return;
    const int cell = cellid[i];
    const int slot = atomicAdd(&cursor[cell], 1);
    dstrow[i] = rel[cell] + boff[cell >> 10] + slot;
}

// ---- fused GEMM: R7 structure (best of 9 variants), + T1 XCD swizzle --------
// 8-wave blocks, 128-row tile, 3-deep global_load_lds pipeline, counted
// vmcnt(6), one raw barrier per chunk. FROZEN except blockIdx swizzle.

template<int DIRECT>
__global__ void k_gemm(const float* __restrict__ feats,
                       const float* __restrict__ tail,
                       const int*   __restrict__ dstrow,   // sorted dest (A) or cellid (B)
                       const float* __restrict__ b1,
                       const unsigned short* __restrict__ pw,
                       float* __restrict__ dst,            // h (A) or out (B)
                       float* __restrict__ gstats) {
    __shared__ float S[3 * 12288];                 // 3 stages x (8192 A + 4096 B floats)
    const int t = threadIdx.x;                     // 0..511
    const int w = t >> 6, l = t & 63;
    const int kgrp = l >> 4, l15 = l & 15;
    // T1: XCD-chunked swizzle (bijective: grid 1024 = 8 x 128)
    const int lb = (blockIdx.x & 7) * ((int)gridDim.x >> 3) + (blockIdx.x >> 3);
    const int row0b = lb * 128;
    const int swz = l15 & 7;
    const int lr = w * 16 + l15;

    f32x4 acc[8];
#pragma unroll
    for (int cb = 0; cb < 8; ++cb) {
#pragma unroll
        for (int d = 0; d < 4; ++d) acc[cb][d] = 0.f;
    }

#define STAGE6(stg, ch) do{                                               \
    float* _base = S + (stg) * 12288;                                     \
    _Pragma("unroll")                                                     \
    for (int _i = 0; _i < 4; ++_i) {   /* A: 2048 slots of 16B */         \
        const int _s   = t + _i * 512;                                    \
        const int _row = _s >> 4;                                         \
        const int _c4  = (_s & 15) ^ (_row & 7);                          \
        const int _k   = (ch) * 64 + _c4 * 4;                             \
        const float* _src = (_k < 1016)                                   \
            ? feats + (size_t)(row0b + _row) * CIN + _k                   \
            : tail  + (size_t)(row0b + _row) * 8 + (_k - 1016);           \
        __builtin_amdgcn_global_load_lds(                                 \
            (const __attribute__((address_space(1))) void*)_src,          \
            (__attribute__((address_space(3))) void*)&_base[_s * 4],      \
            16, 0, 0);                                                    \
    }                                                                     \
    _Pragma("unroll")                                                     \
    for (int _i = 0; _i < 2; ++_i) {   /* B: 1024 slots of 16B */         \
        const int _s = t + _i * 512;                                      \
        __builtin_amdgcn_global_load_lds(                                 \
            (const __attribute__((address_space(1))) void*)                \
                (pw + (size_t)(ch) * 8192 + (size_t)_s * 8),              \
            (__attribute__((address_space(3))) void*)&_base[8192 + _s*4], \
            16, 0, 0);                                                    \
    }                                                                     \
}while(0)

    STAGE6(0, 0);
    STAGE6(1, 1);                                  // 12 vm ops in flight
    int cur = 0, nxt2 = 2;                         // (ch)%3, (ch+2)%3
    for (int ch = 0; ch < 16; ++ch) {
        __builtin_amdgcn_sched_barrier(0);
        if (ch == 15) asm volatile("s_waitcnt vmcnt(0)" ::: "memory");
        else          asm volatile("s_waitcnt vmcnt(6)" ::: "memory");
        __builtin_amdgcn_sched_barrier(0);
        __builtin_amdgcn_s_barrier();              // all waves' stage(ch) visible
        __builtin_amdgcn_sched_barrier(0);
        if (ch + 2 < 16) STAGE6(nxt2, ch + 2);     // overwrites buf read in phase ch-1: safe
        const float* bufA = S + cur * 12288;
        const unsigned short* bufB = (const unsigned short*)(bufA + 8192);
#pragma unroll
        for (int ks = 0; ks < 2; ++ks) {
            const int c4a = ks * 8 + kgrp * 2;
            const f32x4 lo = *(const f32x4*)&bufA[lr * 64 + (( c4a      ^ swz) << 2)];
            const f32x4 hi = *(const f32x4*)&bufA[lr * 64 + (((c4a + 1) ^ swz) << 2)];
            const us8 a = cvt8f(lo, hi);
#pragma unroll
            for (int cb = 0; cb < 8; ++cb) {
                const us8 b = *(const us8*)(bufB + (((ks * 8 + cb) * 64) + l) * 8);
                acc[cb] = MF(a, b, acc[cb]);
            }
        }
        __builtin_amdgcn_sched_barrier(0);
        cur  = cur  == 2 ? 0 : cur + 1;
        nxt2 = nxt2 == 2 ? 0 : nxt2 + 1;
    }
#undef STAGE6

    // epilogue: bias+relu; plan A: dense store at sorted row; B: atomic scatter
    int r0[4];
#pragma unroll
    for (int j = 0; j < 4; ++j)
        r0[j] = dstrow[row0b + w * 16 + kgrp * 4 + j];   // C/D: row=(l>>4)*4+reg, col=l&15
    float* grep = gstats + (size_t)((blockIdx.x * 8 + w) & (NREP - 1)) * 256;
#pragma unroll
    for (int cb = 0; cb < 8; ++cb) {
        const int c = cb * 16 + l15;
        const float bias = b1[c];
        float s = 0.f, q = 0.f;
#pragma unroll
        for (int j = 0; j < 4; ++j) {
            float v0 = acc[cb][j] + bias; v0 = v0 > 0.f ? v0 : 0.f;
            if (DIRECT) {
                const int a = r0[j];                     // here dstrow==cellid
                unsafeAtomicAdd(dst + (((size_t)((a >> 15) * COUT + c)) << 15) + (a & 32767), v0);
            } else {
                dst[(size_t)r0[j] * COUT + c] = v0;      // sorted dense store
            }
            s += v0; q += v0 * v0;
        }
        s += __shfl_xor(s, 16); s += __shfl_xor(s, 32);
        q += __shfl_xor(q, 16); q += __shfl_xor(q, 32);
        if (l < 16) {
            unsafeAtomicAdd(grep + c, s);
            unsafeAtomicAdd(grep + COUT + c, q);
        }
    }
}

// ---- finalize BN affine (plan B only; plan A folds this into k_out) --------
__global__ void k_stats(const float* __restrict__ gstats, const float* __restrict__ g1,
                        const float* __restrict__ be1, float* __restrict__ ss) {
    const int c = threadIdx.x;   // 128
    float sm = 0.f, sq = 0.f;
#pragma unroll
    for (int r = 0; r < NREP; ++r) {
        sm += gstats[r * 256 + c];
        sq += gstats[r * 256 + COUT + c];
    }
    const float invn = 1.0f / (float)NPTS;
    const float mean = sm * invn;
    float var = sq * invn - mean * mean;
    var = var < 0.f ? 0.f : var;
    const float sc = g1[c] * rsqrtf(var + 1e-5f);
    ss[c] = sc;
    ss[COUT + c] = be1[c] - mean * sc;
}

// ---- gather sorted h rows per 64-cell block, inline BN stats, transpose ----
// 36 KB LDS -> 4 blocks/CU (2x R7's k_out) for gather-latency overlap. T1
// swizzle keeps each XCD's h/out traffic contiguous. Pad-68 tile: writes
// 2-way (free), reads 16B-aligned.
__global__ __launch_bounds__(256) void k_out(const float* __restrict__ h,
                                             const int* __restrict__ cnt,
                                             const int* __restrict__ rel,
                                             const int* __restrict__ boff,
                                             const float* __restrict__ gstats,
                                             const float* __restrict__ g1,
                                             const float* __restrict__ be1,
                                             float* __restrict__ out) {
    __shared__ float tile[128 * 68];
    __shared__ float linv[64];
    __shared__ float lss[256];
    const int t  = threadIdx.x;
    const int lb = (blockIdx.x & 7) * ((int)gridDim.x >> 3) + (blockIdx.x >> 3);
    const int s0 = lb * 64;
    const int b = s0 >> 15, sp0 = s0 & 32767;
    const int boff0 = boff[s0 >> 10];
    if (t < 64) {
        const int cn = cnt[s0 + t];
        linv[t] = cn > 0 ? 1.0f / (float)cn : 0.f;
    } else if (t >= 128) {
        const int c = t - 128;
        float sm = 0.f, sq = 0.f;
#pragma unroll
        for (int r = 0; r < NREP; ++r) {
            sm += gstats[r * 256 + c];
            sq += gstats[r * 256 + COUT + c];
        }
        const float invn = 1.0f / (float)NPTS;
        const float mean = sm * invn;
        float var = sq * invn - mean * mean;
        var = var < 0.f ? 0.f : var;
        const float sc = g1[c] * rsqrtf(var + 1e-5f);
        lss[c] = sc;
        lss[128 + c] = be1[c] - mean * sc;
    }
    const int q = t & 31, r8 = t >> 5;              // gather mapping
#pragma unroll
    for (int rep = 0; rep < 8; ++rep) {
        const int j = r8 + rep * 8;                 // 64 cells
        const int cj = cnt[s0 + j];
        if (cj > 0) {
            const int st = rel[s0 + j] + boff0;
            f32x4 v; v[0] = v[1] = v[2] = v[3] = 0.f;
            for (int k = 0; k < cj; ++k) {
                const f32x4 hv = *(const f32x4*)&h[(size_t)(st + k) * COUT + q * 4];
                v[0] += hv[0]; v[1] += hv[1]; v[2] += hv[2]; v[3] += hv[3];
            }
#pragma unroll
            for (int d = 0; d < 4; ++d) tile[(q * 4 + d) * 68 + j] = v[d];
        }
    }
    __syncthreads();
    const int qq = t & 15, rr = t >> 4;             // write mapping
#pragma unroll
    for (int p = 0; p < 8; ++p) {
        const int c = p * 16 + rr;
        const float sc = lss[c], sh = lss[128 + c];
        const f32x4 vv = *(const f32x4*)&tile[c * 68 + qq * 4];
        f32x4 o;
#pragma unroll
        for (int d = 0; d < 4; ++d) {
            const float inv = linv[qq * 4 + d];
            o[d] = inv > 0.f ? vv[d] * inv * sc + sh : 0.f;
        }
        *(f32x4*)&out[(((size_t)(b * COUT + c)) << 15) + sp0 + qq * 4] = o;
    }
}

// ---- fallback normalize (plan B) -------------------------------------------
__global__ __launch_bounds__(256) void k_norm_inplace(float* __restrict__ out,
                                                      const int* __restrict__ cnt,
                                                      const float* __restrict__ ss,
                                                      size_t total) {
    const size_t i = ((size_t)blockIdx.x * 256 + threadIdx.x) * 4;
    if (i >= total) return;
    const int c = (int)((i >> 15) & 127);
    const size_t cellb = ((i >> 22) << 15) | (i & 32767);
    f32x4 v = *(f32x4*)&out[i];
    const int4 cn = *(const int4*)&cnt[cellb];
    const float sc = ss[c], sh = ss[COUT + c];
    const int cna[4] = {cn.x, cn.y, cn.z, cn.w};
#pragma unroll
    for (int d = 0; d < 4; ++d)
        v[d] = cna[d] > 0 ? v[d] / (float)cna[d] * sc + sh : 0.f;
    *(f32x4*)&out[i] = v;
}

extern "C" void kernel_launch(void* const* d_in, const int* in_sizes, int n_in,
                              void* d_out, int out_size, void* d_ws, size_t ws_size,
                              hipStream_t stream) {
    const float* xyz   = (const float*)d_in[0];
    const float* nocs  = (const float*)d_in[1];
    const float* feats = (const float*)d_in[2];
    const int*   bidx  = (const int*)d_in[4];
    const float* W1    = (const float*)d_in[6];
    const float* b1    = (const float*)d_in[7];
    const float* g1    = (const float*)d_in[8];
    const float* be1   = (const float*)d_in[9];
    float* out = (float*)d_out;
    float* ws  = (float*)d_ws;

    const size_t HF  = (size_t)NPTS * COUT;               // 16,777,216 floats
    const size_t STF = NREP * 256;
    // plan A (4B units): h | cnt | st | cur | rel | bof | dstrow | ss | tail | cid | pw
    const size_t oA_h    = 0;
    const size_t oA_cnt  = HF;
    const size_t oA_st   = oA_cnt + NCELLS;               // cnt+st = one zero span
    const size_t oA_cur  = oA_st + STF;                   // zeroed by k_scanA
    const size_t oA_rel  = oA_cur + NCELLS;
    const size_t oA_bof  = oA_rel + NCELLS;
    const size_t oA_dr   = oA_bof + 512;
    const size_t oA_ss   = oA_dr + NPTS;
    const size_t oA_tail = oA_ss + 256;
    const size_t oA_cid  = oA_tail + (size_t)NPTS * 8;
    const size_t oA_pw   = oA_cid + NPTS;
    const size_t needA   = (oA_pw + 65536) * sizeof(float);   // pw = 131072 u16
    const bool planA = ws_size >= needA;

    // plan B (4B units): cnt | st | ss | tail | cid | pw
    const size_t oB_cnt = 0, oB_st = NCELLS, oB_ss = oB_st + STF,
                 oB_tail = oB_ss + 256, oB_cid = oB_tail + (size_t)NPTS * 8,
                 oB_pw = oB_cid + NPTS;

    float* h   = planA ? ws + oA_h : nullptr;
    int*   cnt = (int*)(ws + (planA ? oA_cnt : oB_cnt));
    float* st  = ws + (planA ? oA_st : oB_st);
    int*   cur = planA ? (int*)(ws + oA_cur) : nullptr;
    int*   rel = planA ? (int*)(ws + oA_rel) : nullptr;
    int*   bof = planA ? (int*)(ws + oA_bof) : nullptr;
    int*   dr  = planA ? (int*)(ws + oA_dr) : nullptr;
    float* ssb = ws + (planA ? oA_ss : oB_ss);
    float* tl  = ws + (planA ? oA_tail : oB_tail);
    int*   cid = (int*)(ws + (planA ? oA_cid : oB_cid));
    unsigned short* pw = (unsigned short*)(ws + (planA ? oA_pw : oB_pw));

    // merged pack + zero (cnt+stats span; cursor zeroed inside k_scanA)
    k_zp<<<576, 256, 0, stream>>>(W1, pw, (int4*)cnt, (int)((NCELLS + STF) / 4));
    if (!planA) hipMemsetAsync(out, 0, (size_t)out_size * sizeof(float), stream);

    k_prep<<<NPTS / 256, 256, 0, stream>>>(xyz, nocs, feats, bidx, tl, cid, cnt);
    if (planA) {
        k_scanA<<<512, 256, 0, stream>>>(cnt, rel, bof, (int4*)cur);
        k_scanB<<<1, 256, 0, stream>>>(bof, bof);
        k_fill<<<NPTS / 256, 256, 0, stream>>>(cid, rel, bof, cur, dr);
        k_gemm<0><<<NPTS / 128, 512, 0, stream>>>(feats, tl, dr, b1, pw, h, st);
        k_out<<<NCELLS / 64, 256, 0, stream>>>(h, cnt, rel, bof, st, g1, be1, out);
    } else {
        k_gemm<1><<<NPTS / 128, 512, 0, stream>>>(feats, tl, cid, b1, pw, out, st);
        k_stats<<<1, 128, 0, stream>>>(st, g1, be1, ssb);
        const size_t total = (size_t)out_size;
        k_norm_inplace<<<(unsigned)((total + 1023) / 1024), 256, 0, stream>>>(out, cnt, ssb, total);
    }
    (void)in_sizes; (void)n_in; (void)d_in;
}